// Round 2
// baseline (182.451 us; speedup 1.0000x reference)
//
#include <hip/hip_runtime.h>
#include <hip/hip_bf16.h>

// FeaStNet NeighbourAssignment — 3 launches:
//   k1_pre : ST[i][0:8]=s_i, ST[i][8:16]=exp(t_i) via bf16 MFMA;
//            xbf=bf16(x); WtB=bf16(Wcat^T); rowptr from sorted dst.
//   k3_mfma: one wave per node. 32-edge chunks, software-pipelined depth 1:
//            gathers for chunk c+1 issue before compute of chunk c.
//            q[e][m] softmax (8-lane groups) -> qt[16][40] LDS;
//            x rows -> xt[4 ct][32 e][16 c] LDS ([4][16] subtile geometry);
//            B-frags via 8x ds_read_b64_tr_b16: each lane reads its OWN
//            8 consecutive bytes (lane-linear, like ds_read_b64), HW
//            transposes within 16-lane groups -> out[l][j]=subtile[j][l&15].
//            G[16,64] += QT[16,32] @ X[32,64] via 4x mfma 16x16x32.
//   k4_mfma: out = (Gbf @ Wcat + R @ b)/8 via bf16 MFMA; W read straight from
//            global (64KB, L2-resident — LDS staging removed for occupancy).

#define CDIM 64
#define SDIM 8

typedef __bf16 bf16x8 __attribute__((ext_vector_type(8)));
typedef __bf16 bf16x4 __attribute__((ext_vector_type(4)));
typedef float f32x4 __attribute__((ext_vector_type(4)));

// blocks [0,nbN): ST+xbf via MFMA ; [nbN,nbN+128): WtB ; rest: rowptr
__global__ __launch_bounds__(256) void k1_pre(
    const float* __restrict__ x, const float* __restrict__ Ws,
    const float* __restrict__ bs, const float* __restrict__ Wt,
    const float* __restrict__ bt, const float* __restrict__ W,
    const int* __restrict__ dst, float* __restrict__ ST,
    __hip_bfloat16* __restrict__ xbf, __hip_bfloat16* __restrict__ WtB,
    int* __restrict__ rowptr, int N, int E, int nbN) {
  int bid = blockIdx.x;
  if (bid >= nbN + 128) {  // rowptr build (dst sorted)
    int e = (bid - nbN - 128) * 256 + threadIdx.x;
    if (e >= E) return;
    int a = dst[e];
    int bnd = (e + 1 < E) ? dst[e + 1] : N;
    if (e == 0) {
      for (int d = 0; d <= a; ++d) rowptr[d] = 0;
    }
    for (int d = a + 1; d <= bnd; ++d) rowptr[d] = e + 1;
    return;
  }
  if (bid >= nbN) {  // Wcat[512][64] -> WtB[64][512] bf16
    int t = (bid - nbN) * 256 + threadIdx.x;  // 0..32767
    int o = t >> 9, k = t & 511;
    WtB[t] = __float2bfloat16(W[(size_t)k * 64 + o]);
    return;
  }

  // ---- ST + xbf for 64 nodes via MFMA ----
  __shared__ __hip_bfloat16 wst[16 * 72];  // WstT[n][k], stride 72
  __shared__ float bst[16];
  int t = threadIdx.x;
#pragma unroll
  for (int j = 0; j < 4; ++j) {
    int idx = t * 4 + j;  // 0..1023
    int n = idx >> 6, k = idx & 63;
    float v = (n < 8) ? Ws[k * 8 + n] : Wt[k * 8 + (n - 8)];
    wst[n * 72 + k] = __float2bfloat16(v);
  }
  if (t < 16) bst[t] = (t < 8) ? bs[t] : bt[t - 8];
  __syncthreads();

  int wave = t >> 6, lane = t & 63;
  int r = lane & 15, q = lane >> 4;
  int node = bid * 64 + wave * 16 + r;
  int nodec = node < N ? node : N - 1;
  const float* xr = x + (size_t)nodec * CDIM;

  bf16x8 afrag[2];
#pragma unroll
  for (int kt = 0; kt < 2; ++kt) {
    float4 u0 = *(const float4*)(xr + kt * 32 + q * 8);
    float4 u1 = *(const float4*)(xr + kt * 32 + q * 8 + 4);
    union { bf16x8 v; __hip_bfloat16 h[8]; } a;
    a.h[0] = __float2bfloat16(u0.x); a.h[1] = __float2bfloat16(u0.y);
    a.h[2] = __float2bfloat16(u0.z); a.h[3] = __float2bfloat16(u0.w);
    a.h[4] = __float2bfloat16(u1.x); a.h[5] = __float2bfloat16(u1.y);
    a.h[6] = __float2bfloat16(u1.z); a.h[7] = __float2bfloat16(u1.w);
    afrag[kt] = a.v;
    if (node < N)
      *(bf16x8*)(xbf + (size_t)node * CDIM + kt * 32 + q * 8) = a.v;
  }

  bf16x8 bf0 = *(const bf16x8*)(wst + r * 72 + q * 8);
  bf16x8 bf1 = *(const bf16x8*)(wst + r * 72 + 32 + q * 8);

  f32x4 acc = {0, 0, 0, 0};
  acc = __builtin_amdgcn_mfma_f32_16x16x32_bf16(afrag[0], bf0, acc, 0, 0, 0);
  acc = __builtin_amdgcn_mfma_f32_16x16x32_bf16(afrag[1], bf1, acc, 0, 0, 0);

  int m = lane & 15;
#pragma unroll
  for (int v = 0; v < 4; ++v) {
    int nd = bid * 64 + wave * 16 + q * 4 + v;
    if (nd >= N) continue;
    float val = acc[v] + bst[m];
    if (m >= 8) val = __expf(val);  // store exp(t)
    ST[nd * 16 + m] = val;
  }
}

// One wave per node; 32-edge chunks through MFMA, pipelined depth 1.
// MFMA layouts (gfx950 16x16x32 bf16, m89/m120-verified):
//   A: a[j]=A[lane&15][(lane>>4)*8+j] ; B: b[j]=B[(lane>>4)*8+j][lane&15]
//   D: reg v -> row=(lane>>4)*4+v, col=lane&15
// xt layout: [ct 0..3][e 0..31][c 0..15] bf16 = 8x [4][16] subtiles per ct.
// tr_read semantics (m156/m162): lane supplies addr of its own 8 consecutive
// bytes; within a 16-lane group supplying base+(l&15)*8, out[l][j] =
// subtile_at_base[j][l&15]. Group q3 base = xt + q3*256 (+128 for 2nd
// subtile, +1024 per channel tile) -> b.h[j] = X[q3*8+j][mp] of tile ct.
__global__ __launch_bounds__(256, 4) void k3_mfma(
    const __hip_bfloat16* __restrict__ xbf, const int* __restrict__ src,
    const int* __restrict__ rowptr, const float* __restrict__ ST,
    __hip_bfloat16* __restrict__ Gbf, float* __restrict__ R, int N) {
  __shared__ __hip_bfloat16 qt_s[4][16 * 40];      // [wave][m'][k], stride 40
  __shared__ __hip_bfloat16 xt_s[4][4 * 32 * 16];  // [wave][ct][e][c]

  int wave = threadIdx.x >> 6;
  int lane = threadIdx.x & 63;
  int i = blockIdx.x * 4 + wave;
  if (i >= N) return;  // wave-private LDS, no barriers

  int mm = lane & 7;   // m for softmax / channel-chunk for gather
  int kk = lane >> 3;  // edge-in-group for softmax & gather
  int mp = lane & 15;  // MFMA row/col
  int q3 = lane >> 4;  // MFMA quad

  __hip_bfloat16* qt = &qt_s[wave][0];
  __hip_bfloat16* xt = &xt_s[wave][0];

  // zero qt rows 8..15 once (A rows 8-15 -> D rows 8-15 = 0, never stored)
  __hip_bfloat16 z0 = __float2bfloat16(0.0f);
#pragma unroll
  for (int z = 0; z < 5; ++z) qt[320 + z * 64 + lane] = z0;

  int lo = rowptr[i];
  int hi = rowptr[i + 1];
  float uv = __expf(ST[i * 16 + mm]);  // e^{s_m}

  // per-lane LDS addresses (loop-invariant).
  // tr_read: lane-linear b64 address within the group's subtile (l&15)*8.
  unsigned rd_addr = (unsigned)(uintptr_t)xt + (unsigned)q3 * 256u +
                     (unsigned)mp * 8u;
  __hip_bfloat16* xw = xt + (mm >> 1) * 512 + (mm & 1) * 8;  // + e*16 elems

  f32x4 acc0 = {0, 0, 0, 0}, acc1 = {0, 0, 0, 0};
  f32x4 acc2 = {0, 0, 0, 0}, acc3 = {0, 0, 0, 0};
  float racc = 0.f;

  if (lo < hi) {
    int ecl = hi - 1;
    int iv[4], niv[4];
    bf16x8 xv[4];
    float tv[4];

    // prologue: chunk-0 indices + data gathers, chunk-1 indices
#pragma unroll
    for (int g = 0; g < 4; ++g) {
      int ek = lo + g * 8 + kk;
      iv[g] = src[ek < ecl ? ek : ecl];
    }
#pragma unroll
    for (int g = 0; g < 4; ++g)
      xv[g] = *(const bf16x8*)(xbf + (size_t)iv[g] * CDIM + mm * 8);
#pragma unroll
    for (int g = 0; g < 4; ++g) tv[g] = ST[iv[g] * 16 + 8 + mm];
    if (lo + 32 < hi) {
#pragma unroll
      for (int g = 0; g < 4; ++g) {
        int ek = lo + 32 + g * 8 + kk;
        niv[g] = src[ek < ecl ? ek : ecl];
      }
    }

    for (int c0 = lo; c0 < hi; c0 += 32) {
      bool hasn = (c0 + 32 < hi);  // wave-uniform
      bf16x8 nxv[4];
      float ntv[4];
      int nniv[4];
      if (hasn) {
        // issue next-chunk data gathers (consumed next iteration)
#pragma unroll
        for (int g = 0; g < 4; ++g)
          nxv[g] = *(const bf16x8*)(xbf + (size_t)niv[g] * CDIM + mm * 8);
#pragma unroll
        for (int g = 0; g < 4; ++g) ntv[g] = ST[niv[g] * 16 + 8 + mm];
        if (c0 + 64 < hi) {
#pragma unroll
          for (int g = 0; g < 4; ++g) {
            int ek = c0 + 64 + g * 8 + kk;
            nniv[g] = src[ek < ecl ? ek : ecl];
          }
        }
      }

      // softmax per 8-edge group; q -> qt (transposed, bf16)
#pragma unroll
      for (int g = 0; g < 4; ++g) {
        float w = uv * tv[g];
        float ssum = w + __shfl_xor(w, 1);
        ssum += __shfl_xor(ssum, 2);
        ssum += __shfl_xor(ssum, 4);
        float qv = w * __frcp_rn(ssum);
        if (c0 + g * 8 + kk >= hi) qv = 0.f;  // padded slot
        racc += qv;
        qt[mm * 40 + g * 8 + kk] = __float2bfloat16(qv);
      }

      // x rows -> xt subtiles (b128, conflict-free)
#pragma unroll
      for (int g = 0; g < 4; ++g)
        *(bf16x8*)(xw + (g * 8 + kk) * 16) = xv[g];

      // A-frag: one contiguous b128 from qt
      bf16x8 afrag = *(const bf16x8*)(qt + mp * 40 + q3 * 8);

      // B-frags: 8x HW-transpose reads (lane-linear b64 per subtile)
      bf16x4 t0, t1, t2, t3, t4, t5, t6, t7;
      asm volatile(
          "ds_read_b64_tr_b16 %0, %8 offset:0\n\t"
          "ds_read_b64_tr_b16 %1, %8 offset:128\n\t"
          "ds_read_b64_tr_b16 %2, %8 offset:1024\n\t"
          "ds_read_b64_tr_b16 %3, %8 offset:1152\n\t"
          "ds_read_b64_tr_b16 %4, %8 offset:2048\n\t"
          "ds_read_b64_tr_b16 %5, %8 offset:2176\n\t"
          "ds_read_b64_tr_b16 %6, %8 offset:3072\n\t"
          "ds_read_b64_tr_b16 %7, %8 offset:3200"
          : "=&v"(t0), "=&v"(t1), "=&v"(t2), "=&v"(t3),
            "=&v"(t4), "=&v"(t5), "=&v"(t6), "=&v"(t7)
          : "v"(rd_addr)
          : "memory");
      asm volatile("s_waitcnt lgkmcnt(0)" ::: "memory");
      __builtin_amdgcn_sched_barrier(0);  // rule #18: pin MFMAs after the wait

      union { bf16x8 v; bf16x4 h[2]; } b0, b1, b2, b3;
      b0.h[0] = t0; b0.h[1] = t1;
      b1.h[0] = t2; b1.h[1] = t3;
      b2.h[0] = t4; b2.h[1] = t5;
      b3.h[0] = t6; b3.h[1] = t7;

      acc0 = __builtin_amdgcn_mfma_f32_16x16x32_bf16(afrag, b0.v, acc0, 0, 0, 0);
      acc1 = __builtin_amdgcn_mfma_f32_16x16x32_bf16(afrag, b1.v, acc1, 0, 0, 0);
      acc2 = __builtin_amdgcn_mfma_f32_16x16x32_bf16(afrag, b2.v, acc2, 0, 0, 0);
      acc3 = __builtin_amdgcn_mfma_f32_16x16x32_bf16(afrag, b3.v, acc3, 0, 0, 0);

      if (hasn) {
#pragma unroll
        for (int g = 0; g < 4; ++g) {
          iv[g] = niv[g];
          xv[g] = nxv[g];
          tv[g] = ntv[g];
          niv[g] = nniv[g];
        }
      }
    }
  }

  // G write: D reg v -> row m=q3*4+v (keep m<8), col mp, tile t
  if (q3 < 2) {
    __hip_bfloat16* Gi = Gbf + (size_t)i * 512;
#pragma unroll
    for (int v = 0; v < 4; ++v) {
      int m = q3 * 4 + v;
      Gi[m * 64 + 0 + mp]  = __float2bfloat16(acc0[v]);
      Gi[m * 64 + 16 + mp] = __float2bfloat16(acc1[v]);
      Gi[m * 64 + 32 + mp] = __float2bfloat16(acc2[v]);
      Gi[m * 64 + 48 + mp] = __float2bfloat16(acc3[v]);
    }
  }

  racc += __shfl_xor(racc, 8);
  racc += __shfl_xor(racc, 16);
  racc += __shfl_xor(racc, 32);
  if (lane < 8) R[(size_t)i * 8 + lane] = racc;
}

// out[N,64] = (Gbf[N,512] @ Wcat[512,64] + R[N,8] @ b[8,64]) / 8 via bf16 MFMA.
// WtB (64KB) read directly from global: L2-resident across all blocks; the
// former 66.5KB LDS tile capped occupancy at 2 blocks/CU for a BW-bound kernel.
__global__ __launch_bounds__(256) void k4_mfma(
    const __hip_bfloat16* __restrict__ Gbf, const float* __restrict__ R,
    const __hip_bfloat16* __restrict__ WtB, const float* __restrict__ bias,
    float* __restrict__ out, int N) {
  int wave = threadIdx.x >> 6;
  int lane = threadIdx.x & 63;
  int r0 = (blockIdx.x * 4 + wave) * 16;
  if (r0 >= N) return;

  int m = lane & 15;
  int q = lane >> 4;
  const __bf16* abase = (const __bf16*)(Gbf + (size_t)(r0 + m) * 512) + q * 8;
  const __bf16* wbase = (const __bf16*)WtB + (size_t)m * 512 + q * 8;

  f32x4 acc0 = {0, 0, 0, 0}, acc1 = {0, 0, 0, 0};
  f32x4 acc2 = {0, 0, 0, 0}, acc3 = {0, 0, 0, 0};
#pragma unroll
  for (int kt = 0; kt < 16; ++kt) {
    bf16x8 a = *(const bf16x8*)(abase + kt * 32);
    bf16x8 b0 = *(const bf16x8*)(wbase + 0 * 8192 + kt * 32);
    bf16x8 b1 = *(const bf16x8*)(wbase + 1 * 8192 + kt * 32);
    bf16x8 b2 = *(const bf16x8*)(wbase + 2 * 8192 + kt * 32);
    bf16x8 b3 = *(const bf16x8*)(wbase + 3 * 8192 + kt * 32);
    acc0 = __builtin_amdgcn_mfma_f32_16x16x32_bf16(a, b0, acc0, 0, 0, 0);
    acc1 = __builtin_amdgcn_mfma_f32_16x16x32_bf16(a, b1, acc1, 0, 0, 0);
    acc2 = __builtin_amdgcn_mfma_f32_16x16x32_bf16(a, b2, acc2, 0, 0, 0);
    acc3 = __builtin_amdgcn_mfma_f32_16x16x32_bf16(a, b3, acc3, 0, 0, 0);
  }

#pragma unroll
  for (int v = 0; v < 4; ++v) {
    int ri = r0 + q * 4 + v;
    if (ri >= N) continue;
    const float* Ri = R + (size_t)ri * 8;
    float b0s = 0, b1s = 0, b2s = 0, b3s = 0;
#pragma unroll
    for (int mm = 0; mm < 8; ++mm) {
      float rv = Ri[mm];
      b0s = fmaf(rv, bias[mm * 64 + 0 + m], b0s);
      b1s = fmaf(rv, bias[mm * 64 + 16 + m], b1s);
      b2s = fmaf(rv, bias[mm * 64 + 32 + m], b2s);
      b3s = fmaf(rv, bias[mm * 64 + 48 + m], b3s);
    }
    float* orow = out + (size_t)ri * 64;
    orow[0 + m]  = (acc0[v] + b0s) * 0.125f;
    orow[16 + m] = (acc1[v] + b1s) * 0.125f;
    orow[32 + m] = (acc2[v] + b2s) * 0.125f;
    orow[48 + m] = (acc3[v] + b3s) * 0.125f;
  }
}

extern "C" void kernel_launch(void* const* d_in, const int* in_sizes, int n_in,
                              void* d_out, int out_size, void* d_ws, size_t ws_size,
                              hipStream_t stream) {
  const float* x  = (const float*)d_in[0];   // [N,64]
  const int* src  = (const int*)d_in[1];     // [E]
  const int* dst  = (const int*)d_in[2];     // [E] sorted
  const float* W  = (const float*)d_in[3];   // [8,64,64] == Wcat[512,64]
  const float* b  = (const float*)d_in[4];   // [8,64]
  const float* Ws = (const float*)d_in[5];   // [64,8]
  const float* bs = (const float*)d_in[6];   // [8]
  const float* Wt = (const float*)d_in[7];   // [64,8]
  const float* bt = (const float*)d_in[8];   // [8]
  int N = in_sizes[0] / CDIM;
  int E = in_sizes[1];
  float* out = (float*)d_out;

  float* ST = (float*)d_ws;                                      // N*16 f32
  __hip_bfloat16* Gbf = (__hip_bfloat16*)(ST + (size_t)N * 16);  // N*512 bf16
  float* R  = (float*)(Gbf + (size_t)N * 512);                   // N*8 f32
  __hip_bfloat16* WtB = (__hip_bfloat16*)(R + (size_t)N * 8);    // 64*512 bf16
  __hip_bfloat16* xbf = WtB + 64 * 512;                          // N*64 bf16
  int* rowptr = (int*)(xbf + (size_t)N * CDIM);                  // N+1 i32

  int nbN = (N + 63) / 64;
  int nbE = (E + 255) / 256;
  k1_pre<<<nbN + 128 + nbE, 256, 0, stream>>>(x, Ws, bs, Wt, bt, W, dst, ST,
                                              xbf, WtB, rowptr, N, E, nbN);
  k3_mfma<<<(N + 3) / 4, 256, 0, stream>>>(xbf, src, rowptr, ST, Gbf, R, N);
  int mtiles = (N + 15) / 16;
  k4_mfma<<<(mtiles + 3) / 4, 256, 0, stream>>>(Gbf, R, WtB, b, out, N);
}

// Round 3
// 158.159 us; speedup vs baseline: 1.1536x; 1.1536x over previous
//
#include <hip/hip_runtime.h>
#include <hip/hip_bf16.h>

// FeaStNet NeighbourAssignment — 3 launches:
//   k1_pre : ST[i][0:8]=s_i, ST[i][8:16]=exp(t_i) via bf16 MFMA;
//            xbf=bf16(x); WtB=bf16(Wcat^T); rowptr from sorted dst.
//   k3_mfma: one wave per node. 32-edge chunks, software-pipelined depth 1.
//            Memory-roofline-bound on random per-edge 128B row gathers
//            (~3.3 TB/s achieved); LDS structure not on critical path.
//   k4_mfma: out = (Gbf @ Wcat + R @ b)/8 via bf16 MFMA. W^T staged in LDS
//            (66.5KB padded); 1024-thread blocks -> 2 blocks x 16 waves =
//            32 waves/CU (was 8 at 256 threads) for the Gbf stream.

#define CDIM 64
#define SDIM 8

typedef __bf16 bf16x8 __attribute__((ext_vector_type(8)));
typedef __bf16 bf16x4 __attribute__((ext_vector_type(4)));
typedef float f32x4 __attribute__((ext_vector_type(4)));

// blocks [0,nbN): ST+xbf via MFMA ; [nbN,nbN+128): WtB ; rest: rowptr
__global__ __launch_bounds__(256) void k1_pre(
    const float* __restrict__ x, const float* __restrict__ Ws,
    const float* __restrict__ bs, const float* __restrict__ Wt,
    const float* __restrict__ bt, const float* __restrict__ W,
    const int* __restrict__ dst, float* __restrict__ ST,
    __hip_bfloat16* __restrict__ xbf, __hip_bfloat16* __restrict__ WtB,
    int* __restrict__ rowptr, int N, int E, int nbN) {
  int bid = blockIdx.x;
  if (bid >= nbN + 128) {  // rowptr build (dst sorted)
    int e = (bid - nbN - 128) * 256 + threadIdx.x;
    if (e >= E) return;
    int a = dst[e];
    int bnd = (e + 1 < E) ? dst[e + 1] : N;
    if (e == 0) {
      for (int d = 0; d <= a; ++d) rowptr[d] = 0;
    }
    for (int d = a + 1; d <= bnd; ++d) rowptr[d] = e + 1;
    return;
  }
  if (bid >= nbN) {  // Wcat[512][64] -> WtB[64][512] bf16
    int t = (bid - nbN) * 256 + threadIdx.x;  // 0..32767
    int o = t >> 9, k = t & 511;
    WtB[t] = __float2bfloat16(W[(size_t)k * 64 + o]);
    return;
  }

  // ---- ST + xbf for 64 nodes via MFMA ----
  __shared__ __hip_bfloat16 wst[16 * 72];  // WstT[n][k], stride 72
  __shared__ float bst[16];
  int t = threadIdx.x;
#pragma unroll
  for (int j = 0; j < 4; ++j) {
    int idx = t * 4 + j;  // 0..1023
    int n = idx >> 6, k = idx & 63;
    float v = (n < 8) ? Ws[k * 8 + n] : Wt[k * 8 + (n - 8)];
    wst[n * 72 + k] = __float2bfloat16(v);
  }
  if (t < 16) bst[t] = (t < 8) ? bs[t] : bt[t - 8];
  __syncthreads();

  int wave = t >> 6, lane = t & 63;
  int r = lane & 15, q = lane >> 4;
  int node = bid * 64 + wave * 16 + r;
  int nodec = node < N ? node : N - 1;
  const float* xr = x + (size_t)nodec * CDIM;

  bf16x8 afrag[2];
#pragma unroll
  for (int kt = 0; kt < 2; ++kt) {
    float4 u0 = *(const float4*)(xr + kt * 32 + q * 8);
    float4 u1 = *(const float4*)(xr + kt * 32 + q * 8 + 4);
    union { bf16x8 v; __hip_bfloat16 h[8]; } a;
    a.h[0] = __float2bfloat16(u0.x); a.h[1] = __float2bfloat16(u0.y);
    a.h[2] = __float2bfloat16(u0.z); a.h[3] = __float2bfloat16(u0.w);
    a.h[4] = __float2bfloat16(u1.x); a.h[5] = __float2bfloat16(u1.y);
    a.h[6] = __float2bfloat16(u1.z); a.h[7] = __float2bfloat16(u1.w);
    afrag[kt] = a.v;
    if (node < N)
      *(bf16x8*)(xbf + (size_t)node * CDIM + kt * 32 + q * 8) = a.v;
  }

  bf16x8 bf0 = *(const bf16x8*)(wst + r * 72 + q * 8);
  bf16x8 bf1 = *(const bf16x8*)(wst + r * 72 + 32 + q * 8);

  f32x4 acc = {0, 0, 0, 0};
  acc = __builtin_amdgcn_mfma_f32_16x16x32_bf16(afrag[0], bf0, acc, 0, 0, 0);
  acc = __builtin_amdgcn_mfma_f32_16x16x32_bf16(afrag[1], bf1, acc, 0, 0, 0);

  int m = lane & 15;
#pragma unroll
  for (int v = 0; v < 4; ++v) {
    int nd = bid * 64 + wave * 16 + q * 4 + v;
    if (nd >= N) continue;
    float val = acc[v] + bst[m];
    if (m >= 8) val = __expf(val);  // store exp(t)
    ST[nd * 16 + m] = val;
  }
}

// One wave per node; 32-edge chunks through MFMA, pipelined depth 1.
// MFMA layouts (gfx950 16x16x32 bf16, m89/m120-verified):
//   A: a[j]=A[lane&15][(lane>>4)*8+j] ; B: b[j]=B[(lane>>4)*8+j][lane&15]
//   D: reg v -> row=(lane>>4)*4+v, col=lane&15
// xt layout: [ct 0..3][e 0..31][c 0..15] bf16 = 8x [4][16] subtiles per ct.
// tr_read: lane supplies addr of its own 8 consecutive bytes; within a
// 16-lane group at base+(l&15)*8, out[l][j] = subtile_at_base[j][l&15].
__global__ __launch_bounds__(256, 4) void k3_mfma(
    const __hip_bfloat16* __restrict__ xbf, const int* __restrict__ src,
    const int* __restrict__ rowptr, const float* __restrict__ ST,
    __hip_bfloat16* __restrict__ Gbf, float* __restrict__ R, int N) {
  __shared__ __hip_bfloat16 qt_s[4][16 * 40];      // [wave][m'][k], stride 40
  __shared__ __hip_bfloat16 xt_s[4][4 * 32 * 16];  // [wave][ct][e][c]

  int wave = threadIdx.x >> 6;
  int lane = threadIdx.x & 63;
  int i = blockIdx.x * 4 + wave;
  if (i >= N) return;  // wave-private LDS, no barriers

  int mm = lane & 7;   // m for softmax / channel-chunk for gather
  int kk = lane >> 3;  // edge-in-group for softmax & gather
  int mp = lane & 15;  // MFMA row/col
  int q3 = lane >> 4;  // MFMA quad

  __hip_bfloat16* qt = &qt_s[wave][0];
  __hip_bfloat16* xt = &xt_s[wave][0];

  // zero qt rows 8..15 once (A rows 8-15 -> D rows 8-15 = 0, never stored)
  __hip_bfloat16 z0 = __float2bfloat16(0.0f);
#pragma unroll
  for (int z = 0; z < 5; ++z) qt[320 + z * 64 + lane] = z0;

  int lo = rowptr[i];
  int hi = rowptr[i + 1];
  float uv = __expf(ST[i * 16 + mm]);  // e^{s_m}

  // per-lane LDS addresses (loop-invariant).
  unsigned rd_addr = (unsigned)(uintptr_t)xt + (unsigned)q3 * 256u +
                     (unsigned)mp * 8u;
  __hip_bfloat16* xw = xt + (mm >> 1) * 512 + (mm & 1) * 8;  // + e*16 elems

  f32x4 acc0 = {0, 0, 0, 0}, acc1 = {0, 0, 0, 0};
  f32x4 acc2 = {0, 0, 0, 0}, acc3 = {0, 0, 0, 0};
  float racc = 0.f;

  if (lo < hi) {
    int ecl = hi - 1;
    int iv[4], niv[4];
    bf16x8 xv[4];
    float tv[4];

    // prologue: chunk-0 indices + data gathers, chunk-1 indices
#pragma unroll
    for (int g = 0; g < 4; ++g) {
      int ek = lo + g * 8 + kk;
      iv[g] = src[ek < ecl ? ek : ecl];
    }
#pragma unroll
    for (int g = 0; g < 4; ++g)
      xv[g] = *(const bf16x8*)(xbf + (size_t)iv[g] * CDIM + mm * 8);
#pragma unroll
    for (int g = 0; g < 4; ++g) tv[g] = ST[iv[g] * 16 + 8 + mm];
    if (lo + 32 < hi) {
#pragma unroll
      for (int g = 0; g < 4; ++g) {
        int ek = lo + 32 + g * 8 + kk;
        niv[g] = src[ek < ecl ? ek : ecl];
      }
    }

    for (int c0 = lo; c0 < hi; c0 += 32) {
      bool hasn = (c0 + 32 < hi);  // wave-uniform
      bf16x8 nxv[4];
      float ntv[4];
      int nniv[4];
      if (hasn) {
        // issue next-chunk data gathers (consumed next iteration)
#pragma unroll
        for (int g = 0; g < 4; ++g)
          nxv[g] = *(const bf16x8*)(xbf + (size_t)niv[g] * CDIM + mm * 8);
#pragma unroll
        for (int g = 0; g < 4; ++g) ntv[g] = ST[niv[g] * 16 + 8 + mm];
        if (c0 + 64 < hi) {
#pragma unroll
          for (int g = 0; g < 4; ++g) {
            int ek = c0 + 64 + g * 8 + kk;
            nniv[g] = src[ek < ecl ? ek : ecl];
          }
        }
      }

      // softmax per 8-edge group; q -> qt (transposed, bf16)
#pragma unroll
      for (int g = 0; g < 4; ++g) {
        float w = uv * tv[g];
        float ssum = w + __shfl_xor(w, 1);
        ssum += __shfl_xor(ssum, 2);
        ssum += __shfl_xor(ssum, 4);
        float qv = w * __frcp_rn(ssum);
        if (c0 + g * 8 + kk >= hi) qv = 0.f;  // padded slot
        racc += qv;
        qt[mm * 40 + g * 8 + kk] = __float2bfloat16(qv);
      }

      // x rows -> xt subtiles (b128)
#pragma unroll
      for (int g = 0; g < 4; ++g)
        *(bf16x8*)(xw + (g * 8 + kk) * 16) = xv[g];

      // A-frag: one contiguous b128 from qt
      bf16x8 afrag = *(const bf16x8*)(qt + mp * 40 + q3 * 8);

      // B-frags: 8x HW-transpose reads (lane-linear b64 per subtile)
      bf16x4 t0, t1, t2, t3, t4, t5, t6, t7;
      asm volatile(
          "ds_read_b64_tr_b16 %0, %8 offset:0\n\t"
          "ds_read_b64_tr_b16 %1, %8 offset:128\n\t"
          "ds_read_b64_tr_b16 %2, %8 offset:1024\n\t"
          "ds_read_b64_tr_b16 %3, %8 offset:1152\n\t"
          "ds_read_b64_tr_b16 %4, %8 offset:2048\n\t"
          "ds_read_b64_tr_b16 %5, %8 offset:2176\n\t"
          "ds_read_b64_tr_b16 %6, %8 offset:3072\n\t"
          "ds_read_b64_tr_b16 %7, %8 offset:3200"
          : "=&v"(t0), "=&v"(t1), "=&v"(t2), "=&v"(t3),
            "=&v"(t4), "=&v"(t5), "=&v"(t6), "=&v"(t7)
          : "v"(rd_addr)
          : "memory");
      asm volatile("s_waitcnt lgkmcnt(0)" ::: "memory");
      __builtin_amdgcn_sched_barrier(0);  // rule #18: pin MFMAs after the wait

      union { bf16x8 v; bf16x4 h[2]; } b0, b1, b2, b3;
      b0.h[0] = t0; b0.h[1] = t1;
      b1.h[0] = t2; b1.h[1] = t3;
      b2.h[0] = t4; b2.h[1] = t5;
      b3.h[0] = t6; b3.h[1] = t7;

      acc0 = __builtin_amdgcn_mfma_f32_16x16x32_bf16(afrag, b0.v, acc0, 0, 0, 0);
      acc1 = __builtin_amdgcn_mfma_f32_16x16x32_bf16(afrag, b1.v, acc1, 0, 0, 0);
      acc2 = __builtin_amdgcn_mfma_f32_16x16x32_bf16(afrag, b2.v, acc2, 0, 0, 0);
      acc3 = __builtin_amdgcn_mfma_f32_16x16x32_bf16(afrag, b3.v, acc3, 0, 0, 0);

      if (hasn) {
#pragma unroll
        for (int g = 0; g < 4; ++g) {
          iv[g] = niv[g];
          xv[g] = nxv[g];
          tv[g] = ntv[g];
          niv[g] = nniv[g];
        }
      }
    }
  }

  // G write: D reg v -> row m=q3*4+v (keep m<8), col mp, tile t
  if (q3 < 2) {
    __hip_bfloat16* Gi = Gbf + (size_t)i * 512;
#pragma unroll
    for (int v = 0; v < 4; ++v) {
      int m = q3 * 4 + v;
      Gi[m * 64 + 0 + mp]  = __float2bfloat16(acc0[v]);
      Gi[m * 64 + 16 + mp] = __float2bfloat16(acc1[v]);
      Gi[m * 64 + 32 + mp] = __float2bfloat16(acc2[v]);
      Gi[m * 64 + 48 + mp] = __float2bfloat16(acc3[v]);
    }
  }

  racc += __shfl_xor(racc, 8);
  racc += __shfl_xor(racc, 16);
  racc += __shfl_xor(racc, 32);
  if (lane < 8) R[(size_t)i * 8 + lane] = racc;
}

// out[N,64] = (Gbf[N,512] @ Wcat[512,64] + R[N,8] @ b[8,64]) / 8 via bf16 MFMA.
// W^T staged in LDS (padded rows, conflict-free reads). 1024-thread blocks:
// LDS 66.5KB -> 2 blocks/CU x 16 waves = 32 waves/CU (100%), 4x the
// outstanding-load depth of the 256-thread version for the Gbf stream.
__global__ __launch_bounds__(1024) void k4_mfma(
    const __hip_bfloat16* __restrict__ Gbf, const float* __restrict__ R,
    const __hip_bfloat16* __restrict__ WtB, const float* __restrict__ bias,
    float* __restrict__ out, int N) {
  __shared__ float4 btile[64 * 65];  // [n][k] bf16, row = 520 bf16 = 65 float4
  {
    const float4* srcp = (const float4*)WtB;  // 4096 float4
    int t = threadIdx.x;
#pragma unroll
    for (int j = 0; j < 4; ++j) {
      int ci = t + j * 1024;
      btile[(ci >> 6) * 65 + (ci & 63)] = srcp[ci];
    }
  }
  __syncthreads();

  int wave = threadIdx.x >> 6;   // 0..15
  int lane = threadIdx.x & 63;
  int r0 = (blockIdx.x * 16 + wave) * 16;
  if (r0 >= N) return;

  int m = lane & 15;
  int q = lane >> 4;
  const __bf16* abase = (const __bf16*)(Gbf + (size_t)(r0 + m) * 512) + q * 8;
  const __bf16* lbase = (const __bf16*)btile + (size_t)m * 520 + q * 8;

  f32x4 acc0 = {0, 0, 0, 0}, acc1 = {0, 0, 0, 0};
  f32x4 acc2 = {0, 0, 0, 0}, acc3 = {0, 0, 0, 0};
#pragma unroll
  for (int kt = 0; kt < 16; ++kt) {
    bf16x8 a = *(const bf16x8*)(abase + kt * 32);
    bf16x8 b0 = *(const bf16x8*)(lbase + 0 * 520 + kt * 32);
    bf16x8 b1 = *(const bf16x8*)(lbase + 16 * 520 + kt * 32);
    bf16x8 b2 = *(const bf16x8*)(lbase + 32 * 520 + kt * 32);
    bf16x8 b3 = *(const bf16x8*)(lbase + 48 * 520 + kt * 32);
    acc0 = __builtin_amdgcn_mfma_f32_16x16x32_bf16(a, b0, acc0, 0, 0, 0);
    acc1 = __builtin_amdgcn_mfma_f32_16x16x32_bf16(a, b1, acc1, 0, 0, 0);
    acc2 = __builtin_amdgcn_mfma_f32_16x16x32_bf16(a, b2, acc2, 0, 0, 0);
    acc3 = __builtin_amdgcn_mfma_f32_16x16x32_bf16(a, b3, acc3, 0, 0, 0);
  }

#pragma unroll
  for (int v = 0; v < 4; ++v) {
    int ri = r0 + q * 4 + v;
    if (ri >= N) continue;
    const float* Ri = R + (size_t)ri * 8;
    float b0s = 0, b1s = 0, b2s = 0, b3s = 0;
#pragma unroll
    for (int mm = 0; mm < 8; ++mm) {
      float rv = Ri[mm];
      b0s = fmaf(rv, bias[mm * 64 + 0 + m], b0s);
      b1s = fmaf(rv, bias[mm * 64 + 16 + m], b1s);
      b2s = fmaf(rv, bias[mm * 64 + 32 + m], b2s);
      b3s = fmaf(rv, bias[mm * 64 + 48 + m], b3s);
    }
    float* orow = out + (size_t)ri * 64;
    orow[0 + m]  = (acc0[v] + b0s) * 0.125f;
    orow[16 + m] = (acc1[v] + b1s) * 0.125f;
    orow[32 + m] = (acc2[v] + b2s) * 0.125f;
    orow[48 + m] = (acc3[v] + b3s) * 0.125f;
  }
}

extern "C" void kernel_launch(void* const* d_in, const int* in_sizes, int n_in,
                              void* d_out, int out_size, void* d_ws, size_t ws_size,
                              hipStream_t stream) {
  const float* x  = (const float*)d_in[0];   // [N,64]
  const int* src  = (const int*)d_in[1];     // [E]
  const int* dst  = (const int*)d_in[2];     // [E] sorted
  const float* W  = (const float*)d_in[3];   // [8,64,64] == Wcat[512,64]
  const float* b  = (const float*)d_in[4];   // [8,64]
  const float* Ws = (const float*)d_in[5];   // [64,8]
  const float* bs = (const float*)d_in[6];   // [8]
  const float* Wt = (const float*)d_in[7];   // [64,8]
  const float* bt = (const float*)d_in[8];   // [8]
  int N = in_sizes[0] / CDIM;
  int E = in_sizes[1];
  float* out = (float*)d_out;

  float* ST = (float*)d_ws;                                      // N*16 f32
  __hip_bfloat16* Gbf = (__hip_bfloat16*)(ST + (size_t)N * 16);  // N*512 bf16
  float* R  = (float*)(Gbf + (size_t)N * 512);                   // N*8 f32
  __hip_bfloat16* WtB = (__hip_bfloat16*)(R + (size_t)N * 8);    // 64*512 bf16
  __hip_bfloat16* xbf = WtB + 64 * 512;                          // N*64 bf16
  int* rowptr = (int*)(xbf + (size_t)N * CDIM);                  // N+1 i32

  int nbN = (N + 63) / 64;
  int nbE = (E + 255) / 256;
  k1_pre<<<nbN + 128 + nbE, 256, 0, stream>>>(x, Ws, bs, Wt, bt, W, dst, ST,
                                              xbf, WtB, rowptr, N, E, nbN);
  k3_mfma<<<(N + 3) / 4, 256, 0, stream>>>(xbf, src, rowptr, ST, Gbf, R, N);
  int mtiles = (N + 15) / 16;
  k4_mfma<<<(mtiles + 15) / 16, 1024, 0, stream>>>(Gbf, R, WtB, b, out, N);
}